// Round 1
// 1685.585 us; speedup vs baseline: 1.4837x; 1.4837x over previous
//
#include <hip/hip_runtime.h>

#define S 2048
#define D 64
#define TQ 64
#define TK 64
#define NKT (S / TK)
#define KSTR 72  // bf16 elems/row = 144 B: 16B-aligned, breaks 128B bank periodicity
#define PSTR 72

typedef __bf16 bf16_t;
typedef __bf16 bf16x8 __attribute__((ext_vector_type(8)));
typedef __bf16 bf16x4 __attribute__((ext_vector_type(4)));
typedef __bf16 bf16x2 __attribute__((ext_vector_type(2)));
typedef float f32x4 __attribute__((ext_vector_type(4)));

#define MFMA16(a, b, c) __builtin_amdgcn_mfma_f32_16x16x32_bf16((a), (b), (c), 0, 0, 0)

// LDS: U1/U2 (K hi/lo during QK^T, V^T hi/lo during PV) 2*9216
//      + per-wave P hi/lo 2*9216  = 36864 B -> 4 blocks/CU
__launch_bounds__(256, 4)
__global__ void attn_fused(const float* __restrict__ Q,
                           const float* __restrict__ K,
                           const float* __restrict__ V,
                           const int* __restrict__ mask,
                           float* __restrict__ out,
                           float* __restrict__ attn) {
  __shared__ bf16_t U1[TK * KSTR];
  __shared__ bf16_t U2[TK * KSTR];
  __shared__ bf16_t Ph[4][16 * PSTR];
  __shared__ bf16_t Pl[4][16 * PSTR];

  const int tid = threadIdx.x;
  const int w = tid >> 6;    // wave id: owns q rows [16w, 16w+16)
  const int lane = tid & 63;
  const int c = lane & 15;   // MFMA A-row / B-col / C-col
  const int g = lane >> 4;   // MFMA k-slice group / C-row group
  const int head = blockIdx.y;
  const int bb = head >> 4;
  const int q0 = blockIdx.x * TQ;

  const float* Qg = Q + ((size_t)head * S + q0) * D;
  const float* Kg = K + (size_t)head * S * D;
  const float* Vg = V + (size_t)head * S * D;
  const int* mg = mask + bb * S;

  // ---- Q A-fragments in registers, split hi/lo bf16 (row q = 16w + c) ----
  bf16x8 qh[2], ql[2];
  {
    const float* qrow = Qg + (16 * w + c) * D;
#pragma unroll
    for (int kf = 0; kf < 2; ++kf) {
      const float4 x0 = *(const float4*)(qrow + 32 * kf + 8 * g);
      const float4 x1 = *(const float4*)(qrow + 32 * kf + 8 * g + 4);
      const float xx[8] = {x0.x, x0.y, x0.z, x0.w, x1.x, x1.y, x1.z, x1.w};
#pragma unroll
      for (int j = 0; j < 8; ++j) {
        const bf16_t h = (bf16_t)xx[j];
        qh[kf][j] = h;
        ql[kf][j] = (bf16_t)(xx[j] - (float)h);
      }
    }
  }

  // K tile -> U1 (hi) / U2 (lo), layout [key][d], stride KSTR
  auto stage_K = [&](int kt) {
    const float* Kt = Kg + (size_t)kt * TK * D;
    const int cs = tid & 15;  // d-chunk: d = 4*cs..4*cs+3
    const int kr = tid >> 4;
#pragma unroll
    for (int rep = 0; rep < 4; ++rep) {
      const int key = rep * 16 + kr;
      const float4 v = *(const float4*)(Kt + key * D + cs * 4);
      const float vv[4] = {v.x, v.y, v.z, v.w};
      bf16x4 h4, l4;
#pragma unroll
      for (int j = 0; j < 4; ++j) {
        const bf16_t hj = (bf16_t)vv[j];
        h4[j] = hj;
        l4[j] = (bf16_t)(vv[j] - (float)hj);
      }
      *(bf16x4*)&U1[key * KSTR + cs * 4] = h4;
      *(bf16x4*)&U2[key * KSTR + cs * 4] = l4;
    }
  };

  // scores for 4 16-wide key tiles: S = (Qh+Ql)*(Kh+Kl), lo*lo dropped
  auto qk_tiles = [&](f32x4* sacc) {
#pragma unroll
    for (int t = 0; t < 4; ++t) {
      f32x4 acc = {0.f, 0.f, 0.f, 0.f};
#pragma unroll
      for (int kf = 0; kf < 2; ++kf) {
        const int off = (16 * t + c) * KSTR + 32 * kf + 8 * g;
        const bf16x8 kbh = *(const bf16x8*)&U1[off];
        const bf16x8 kbl = *(const bf16x8*)&U2[off];
        acc = MFMA16(qh[kf], kbh, acc);
        acc = MFMA16(qh[kf], kbl, acc);
        acc = MFMA16(ql[kf], kbh, acc);
      }
      sacc[t] = acc;
    }
  };

  float m_i[4], l_i[4];
#pragma unroll
  for (int r = 0; r < 4; ++r) { m_i[r] = -1e30f; l_i[r] = 0.0f; }

  // =============== pass 1: online row max & denom ===============
  for (int kt = 0; kt < NKT; ++kt) {
    __syncthreads();
    stage_K(kt);
    __syncthreads();

    int ma[4];
#pragma unroll
    for (int t = 0; t < 4; ++t) ma[t] = mg[kt * TK + 16 * t + c];

    f32x4 sacc[4];
    qk_tiles(sacc);

#pragma unroll
    for (int r = 0; r < 4; ++r) {
      float sv[4];
#pragma unroll
      for (int t = 0; t < 4; ++t) sv[t] = ma[t] ? sacc[t][r] * 0.125f : -1e30f;
      float tmax = fmaxf(fmaxf(sv[0], sv[1]), fmaxf(sv[2], sv[3]));
#pragma unroll
      for (int off = 1; off < 16; off <<= 1) tmax = fmaxf(tmax, __shfl_xor(tmax, off));
      const float mnew = fmaxf(m_i[r], tmax);
      float tsum = __expf(sv[0] - mnew) + __expf(sv[1] - mnew) +
                   __expf(sv[2] - mnew) + __expf(sv[3] - mnew);
#pragma unroll
      for (int off = 1; off < 16; off <<= 1) tsum += __shfl_xor(tsum, off);
      l_i[r] = l_i[r] * __expf(m_i[r] - mnew) + tsum;
      m_i[r] = mnew;
    }
  }

  float inv_l[4];
#pragma unroll
  for (int r = 0; r < 4; ++r) inv_l[r] = 1.0f / l_i[r];

  f32x4 oacc[4];
  {
    const f32x4 z = {0.f, 0.f, 0.f, 0.f};
#pragma unroll
    for (int nt = 0; nt < 4; ++nt) oacc[nt] = z;
  }

  float* attn_base = attn + ((size_t)head * S + q0) * S;
  bf16_t* ph_w = Ph[w];
  bf16_t* pl_w = Pl[w];

  // =============== pass 2: p = exp(s-m)/l, attn store, O += P.V ===============
  for (int kt = 0; kt < NKT; ++kt) {
    __syncthreads();  // prev PV done with U1/U2
    stage_K(kt);
    __syncthreads();

    int ma[4];
#pragma unroll
    for (int t = 0; t < 4; ++t) ma[t] = mg[kt * TK + 16 * t + c];

    f32x4 sacc[4];
    qk_tiles(sacc);

    __syncthreads();  // all waves done reading K from U1/U2

    // stage V^T (hi/lo) into U1/U2: layout [d][key ^ ((d>>2 & 3)<<3)]
    {
      const float* Vt_g = Vg + (size_t)kt * TK * D;
      const int cs = tid & 15;  // d-chunk: d = 4*cs + dd
      const int kp = tid >> 4;  // key pair
      const int xs = (cs & 3) << 3;
#pragma unroll
      for (int rep = 0; rep < 2; ++rep) {
        const int k0 = 2 * kp + 32 * rep;
        const float4 va = *(const float4*)(Vt_g + (size_t)k0 * D + cs * 4);
        const float4 vb = *(const float4*)(Vt_g + (size_t)(k0 + 1) * D + cs * 4);
        const float aa[4] = {va.x, va.y, va.z, va.w};
        const float bb4[4] = {vb.x, vb.y, vb.z, vb.w};
#pragma unroll
        for (int dd = 0; dd < 4; ++dd) {
          const int drow = 4 * cs + dd;
          const bf16_t ha = (bf16_t)aa[dd];
          const bf16_t hb = (bf16_t)bb4[dd];
          bf16x2 hi2, lo2;
          hi2[0] = ha; hi2[1] = hb;
          lo2[0] = (bf16_t)(aa[dd] - (float)ha);
          lo2[1] = (bf16_t)(bb4[dd] - (float)hb);
          *(bf16x2*)&U1[drow * KSTR + (k0 ^ xs)] = hi2;
          *(bf16x2*)&U2[drow * KSTR + (k0 ^ xs)] = lo2;
        }
      }
    }

    // p (fp32), attn store (nontemporal), P hi/lo into per-wave LDS [q][key]
#pragma unroll
    for (int t = 0; t < 4; ++t) {
#pragma unroll
      for (int r = 0; r < 4; ++r) {
        const float sv = ma[t] ? sacc[t][r] * 0.125f : -1e30f;
        const float pv = __expf(sv - m_i[r]) * inv_l[r];
        __builtin_nontemporal_store(
            pv, &attn_base[(size_t)(16 * w + 4 * g + r) * S + kt * TK + 16 * t + c]);
        const bf16_t hh = (bf16_t)pv;
        ph_w[(4 * g + r) * PSTR + 16 * t + c] = hh;
        pl_w[(4 * g + r) * PSTR + 16 * t + c] = (bf16_t)(pv - (float)hh);
      }
    }

    __syncthreads();  // V^T staged (P is same-wave: in-order LDS)

    // PV: O += (Ph+Pl)*(Vh+Vl), lo*lo dropped
    bf16x8 pah[2], pal[2];
#pragma unroll
    for (int kf = 0; kf < 2; ++kf) {
      pah[kf] = *(const bf16x8*)&ph_w[c * PSTR + 32 * kf + 8 * g];
      pal[kf] = *(const bf16x8*)&pl_w[c * PSTR + 32 * kf + 8 * g];
    }
#pragma unroll
    for (int nt = 0; nt < 4; ++nt) {
      const int dloc = 16 * nt + c;
      const int xv = (c >> 2) << 3;  // ((dloc>>2)&3)<<3
#pragma unroll
      for (int kf = 0; kf < 2; ++kf) {
        const int vo = dloc * KSTR + ((32 * kf + 8 * g) ^ xv);
        const bf16x8 vbh = *(const bf16x8*)&U1[vo];
        const bf16x8 vbl = *(const bf16x8*)&U2[vo];
        oacc[nt] = MFMA16(pah[kf], vbh, oacc[nt]);
        oacc[nt] = MFMA16(pah[kf], vbl, oacc[nt]);
        oacc[nt] = MFMA16(pal[kf], vbh, oacc[nt]);
      }
    }
  }

  // output: out[head][q0 + 16w + 4g + r][16nt + c]
#pragma unroll
  for (int nt = 0; nt < 4; ++nt)
#pragma unroll
    for (int r = 0; r < 4; ++r)
      out[((size_t)head * S + q0 + 16 * w + 4 * g + r) * D + 16 * nt + c] = oacc[nt][r];
}

extern "C" void kernel_launch(void* const* d_in, const int* in_sizes, int n_in,
                              void* d_out, int out_size, void* d_ws, size_t ws_size,
                              hipStream_t stream) {
  (void)in_sizes; (void)n_in; (void)out_size; (void)d_ws; (void)ws_size;
  const float* Q = (const float*)d_in[0];
  const float* K = (const float*)d_in[1];
  const float* V = (const float*)d_in[2];
  const int* mask = (const int*)d_in[3];
  float* out = (float*)d_out;
  float* attn = out + (size_t)4 * 16 * 2048 * 64;  // outputs concatenated: output, attn
  dim3 grid(S / TQ, 4 * 16);
  attn_fused<<<grid, dim3(256), 0, stream>>>(Q, K, V, mask, out, attn);
}